// Round 12
// baseline (164.504 us; speedup 1.0000x reference)
//
#include <hip/hip_runtime.h>

// MHSA fwd MFMA bf16: B=8, N=1024, D=1024, H=16, DK=64. fp32 in/out, bf16 compute.
// Round 12: attention QBLK=256 (32 MFMA/tile/wave, kf/vf reads amortized over
// 2 m-frags, K/V re-fetch halved). GEMMs/prep unchanged from round 11.

typedef __attribute__((ext_vector_type(8))) short bf16x8;
typedef __attribute__((ext_vector_type(4))) float f32x4;

#define GLOAD_LDS16(gp, lp)                                                              \
  __builtin_amdgcn_global_load_lds((const __attribute__((address_space(1))) void*)(gp),  \
                                   (__attribute__((address_space(3))) void*)(lp), 16, 0, 0)

__device__ __forceinline__ unsigned short f2bf(float f) {
  unsigned int u = __float_as_uint(f);
  u += 0x7fffu + ((u >> 16) & 1u);          // RNE
  return (unsigned short)(u >> 16);
}

// ---------------------------------------------------------------------------
// Fused pre-pass: blocks [0,2048) cast x->bf16; [2048,5120) transpose W_qkv;
// [5120,6144) transpose W_o.
// ---------------------------------------------------------------------------
__global__ __launch_bounds__(256) void prep_fused(
    const float* __restrict__ x, unsigned short* __restrict__ x_bf,
    const float* __restrict__ W_qkv, unsigned short* __restrict__ wqkv_t,
    const float* __restrict__ W_o, unsigned short* __restrict__ wo_t) {
  const int b = blockIdx.x;
  if (b < 2048) {
    const int n4 = 8388608 / 4;
    for (int i = b * 256 + threadIdx.x; i < n4; i += 2048 * 256) {
      float4 v = reinterpret_cast<const float4*>(x)[i];
      ushort4 o;
      o.x = f2bf(v.x); o.y = f2bf(v.y); o.z = f2bf(v.z); o.w = f2bf(v.w);
      reinterpret_cast<ushort4*>(x_bf)[i] = o;
    }
  } else {
    __shared__ float tile[32][33];
    const float* W;
    unsigned short* Wt;
    int R = 1024, C, bx, by;
    if (b < 5120) {
      W = W_qkv; Wt = wqkv_t; C = 3072;
      int bb = b - 2048; bx = bb % 96; by = bb / 96;
    } else {
      W = W_o; Wt = wo_t; C = 1024;
      int bb = b - 5120; bx = bb & 31; by = bb >> 5;
    }
    const int tx = threadIdx.x & 31, ty = threadIdx.x >> 5;
    const int c0 = bx * 32, r0 = by * 32;
    #pragma unroll
    for (int i = 0; i < 4; i++) {
      int r = r0 + ty + i * 8;
      tile[ty + i * 8][tx] = W[(size_t)r * C + c0 + tx];
    }
    __syncthreads();
    #pragma unroll
    for (int i = 0; i < 4; i++) {
      int c = c0 + ty + i * 8;
      Wt[(size_t)c * R + r0 + tx] = f2bf(tile[tx][ty + i * 8]);
    }
  }
}

// ---------------------------------------------------------------------------
// GEMM (round-6 proven config): 128x256, BK=64, 512 thr (8 waves = 2M x 4N;
// 64x64 per wave). 3-buf LDS; tile kt+2 staged during tile kt; tile-top
// vmcnt(6). 2 phases x 16 MFMA.
// MODE 0: qkv scatter (Q pre-scaled 0.125, V transposed per head). MODE 1: f32.
// ---------------------------------------------------------------------------
template <int MODE>
__global__ __launch_bounds__(512) void gemm256(
    const unsigned short* __restrict__ A, const unsigned short* __restrict__ Bt,
    const float* __restrict__ bias, unsigned short* __restrict__ qkv_out,
    float* __restrict__ Cout) {
  __shared__ __align__(16) unsigned short As[3][128 * 64];   // 48 KB
  __shared__ __align__(16) unsigned short Bs[3][256 * 64];   // 96 KB
  const int t = threadIdx.x;
  const int lane = t & 63, wid = t >> 6;
  const int lr = lane & 15, g = lane >> 4;
  const int wm = wid >> 2, wn = wid & 3;

  const int nwg = gridDim.x * gridDim.y;
  const int id = blockIdx.x + gridDim.x * blockIdx.y;
  const int sw = (id & 7) * (nwg >> 3) + (id >> 3);
  const int bx = sw % gridDim.x, by = sw / gridDim.x;
  const int row0 = by * 128, col0 = bx * 256;

  const int srow = t >> 3, sch = t & 7;     // 64 rows of 128B

  auto stA = [&](int buf, int kt, int j) {  // j=0..1
    int row = j * 64 + srow;
    int ch = sch ^ (row & 7);
    GLOAD_LDS16(A + (size_t)(row0 + row) * 1024 + kt * 64 + ch * 8,
                (char*)&As[buf][0] + j * 8192 + t * 16);
  };
  auto stB = [&](int buf, int kt, int j) {  // j=0..3
    int row = j * 64 + srow;
    int ch = sch ^ (row & 7);
    GLOAD_LDS16(Bt + (size_t)(col0 + row) * 1024 + kt * 64 + ch * 8,
                (char*)&Bs[buf][0] + j * 8192 + t * 16);
  };
  auto rdA = [&](int buf, int c, int m) -> bf16x8 {
    int r = wm * 64 + m * 16 + lr;
    return *(const bf16x8*)((const char*)&As[buf][0] + r * 128 +
                            ((c * 64 + g * 16) ^ ((r & 7) << 4)));
  };
  auto rdB = [&](int buf, int c, int n) -> bf16x8 {
    int r = wn * 64 + n * 16 + lr;
    return *(const bf16x8*)((const char*)&Bs[buf][0] + r * 128 +
                            ((c * 64 + g * 16) ^ ((r & 7) << 4)));
  };

  f32x4 acc[4][4] = {};

  stA(0, 0, 0); stA(0, 0, 1);
  stB(0, 0, 0); stB(0, 0, 1); stB(0, 0, 2); stB(0, 0, 3);
  stA(1, 1, 0); stA(1, 1, 1);
  stB(1, 1, 0); stB(1, 1, 1); stB(1, 1, 2); stB(1, 1, 3);
  asm volatile("s_waitcnt vmcnt(6)" ::: "memory");
  __builtin_amdgcn_s_barrier();

  for (int kt = 0; kt < 16; kt++) {
    const int buf = kt % 3;
    const int bufn = (kt + 2) % 3;
    const bool pf = (kt <= 13);
    if (kt > 0) {
      if (kt == 15) asm volatile("s_waitcnt vmcnt(0)" ::: "memory");
      else          asm volatile("s_waitcnt vmcnt(6)" ::: "memory");
      __builtin_amdgcn_s_barrier();
    }

    // ---- phase 0: k-step 0 ----
    bf16x8 a0[4], b0[4];
    #pragma unroll
    for (int m = 0; m < 4; m++) a0[m] = rdA(buf, 0, m);
    #pragma unroll
    for (int n = 0; n < 4; n++) b0[n] = rdB(buf, 0, n);
    if (pf) { stA(bufn, kt + 2, 0); stA(bufn, kt + 2, 1); stB(bufn, kt + 2, 0); }
    __builtin_amdgcn_s_barrier();
    asm volatile("s_waitcnt lgkmcnt(0)" ::: "memory");
    __builtin_amdgcn_sched_barrier(0);
    __builtin_amdgcn_s_setprio(1);
    #pragma unroll
    for (int m = 0; m < 4; m++)
      #pragma unroll
      for (int n = 0; n < 4; n++)
        acc[m][n] = __builtin_amdgcn_mfma_f32_16x16x32_bf16(a0[m], b0[n], acc[m][n], 0, 0, 0);
    __builtin_amdgcn_s_setprio(0);
    __builtin_amdgcn_s_barrier();

    // ---- phase 1: k-step 1 ----
    bf16x8 a1[4], b1[4];
    #pragma unroll
    for (int m = 0; m < 4; m++) a1[m] = rdA(buf, 1, m);
    #pragma unroll
    for (int n = 0; n < 4; n++) b1[n] = rdB(buf, 1, n);
    if (pf) { stB(bufn, kt + 2, 1); stB(bufn, kt + 2, 2); stB(bufn, kt + 2, 3); }
    __builtin_amdgcn_s_barrier();
    asm volatile("s_waitcnt lgkmcnt(0)" ::: "memory");
    __builtin_amdgcn_sched_barrier(0);
    __builtin_amdgcn_s_setprio(1);
    #pragma unroll
    for (int m = 0; m < 4; m++)
      #pragma unroll
      for (int n = 0; n < 4; n++)
        acc[m][n] = __builtin_amdgcn_mfma_f32_16x16x32_bf16(a1[m], b1[n], acc[m][n], 0, 0, 0);
    __builtin_amdgcn_s_setprio(0);
    __builtin_amdgcn_s_barrier();
  }

  // ---------------- epilogue ----------------
  if (MODE == 0) {
    const int which = col0 >> 10;   // block-uniform (1024 % 256 == 0)
    if (which == 2) {
      #pragma unroll
      for (int m = 0; m < 4; m++) {
        int row = row0 + wm * 64 + m * 16 + g * 4;
        int bb = row >> 10, nn = row & 1023;
        #pragma unroll
        for (int n = 0; n < 4; n++) {
          int col = col0 + wn * 64 + n * 16 + lr;
          int cc = col & 1023;
          int h = cc >> 6, dk = cc & 63;
          float bv = bias[col];
          ushort4 w;
          w.x = f2bf(acc[m][n][0] + bv);
          w.y = f2bf(acc[m][n][1] + bv);
          w.z = f2bf(acc[m][n][2] + bv);
          w.w = f2bf(acc[m][n][3] + bv);
          size_t idx = ((size_t)2 << 23) + (((size_t)(bb * 16 + h)) << 16) +
                       (size_t)dk * 1024 + nn;
          *(ushort4*)(qkv_out + idx) = w;
        }
      }
    } else {
      #pragma unroll
      for (int m = 0; m < 4; m++) {
        #pragma unroll
        for (int n = 0; n < 4; n++) {
          int col = col0 + wn * 64 + n * 16 + lr;
          int cc = col & 1023;
          int h = cc >> 6, dk = cc & 63;
          #pragma unroll
          for (int r = 0; r < 4; r++) {
            int row = row0 + wm * 64 + m * 16 + g * 4 + r;
            int bb = row >> 10, nn = row & 1023;
            float v = acc[m][n][r] + bias[col];
            if (which == 0) v *= 0.125f;   // fold 1/sqrt(dk) into Q
            size_t idx = ((size_t)which << 23) +
                         (((size_t)((bb * 16 + h) * 1024 + nn)) << 6) + dk;
            qkv_out[idx] = f2bf(v);
          }
        }
      }
    }
  } else {
    #pragma unroll
    for (int m = 0; m < 4; m++) {
      #pragma unroll
      for (int n = 0; n < 4; n++) {
        int col = col0 + wn * 64 + n * 16 + lr;
        #pragma unroll
        for (int r = 0; r < 4; r++) {
          int row = row0 + wm * 64 + m * 16 + g * 4 + r;
          Cout[(size_t)row * 1024 + col] = acc[m][n][r] + bias[col];
        }
      }
    }
  }
}

// ---------------------------------------------------------------------------
// Attention v5: 8 waves, QBLK=256 (32 q-rows/wave = 2 m-frags), KVBLK=64.
// K and V^T staged via swizzled global_load_lds, double-buffered, prefetch
// before compute, one __syncthreads per tile. kf/vf read once per (ks,c),
// used by both m-frags. QK^T -> exp -> P_lds (wave-local) -> PV.
// No max-subtract; den shfl-reduced at end. setprio; XCD swizzle.
// ---------------------------------------------------------------------------
__global__ __launch_bounds__(512) void attn_mfma(
    const unsigned short* __restrict__ qkv, unsigned short* __restrict__ attn_out) {
  __shared__ __align__(16) unsigned short K_lds[2][64 * 64];   // [k][d] swz, 16 KB
  __shared__ __align__(16) unsigned short V_lds[2][64 * 64];   // [d][k] swz, 16 KB
  __shared__ __align__(16) unsigned short P_lds[256 * 64];     // [q][k] swz, 32 KB

  // XCD swizzle: nwg = 512 (divisible by 8), bijective
  const int bid = ((blockIdx.x & 7) << 6) + (blockIdx.x >> 3);
  const int bh = bid >> 2, qt = bid & 3;
  const unsigned short* Qp = qkv + ((size_t)bh << 16);
  const unsigned short* Kp = qkv + (1u << 23) + ((size_t)bh << 16);
  const unsigned short* Vt = qkv + (2u << 23) + ((size_t)bh << 16);  // [dk][n]

  const int t = threadIdx.x;
  const int lane = t & 63, wid = t >> 6;
  const int lr = lane & 15, g = lane >> 4;

  bf16x8 qf[2][2];
  #pragma unroll
  for (int m = 0; m < 2; m++) {
    int qrow = qt * 256 + wid * 32 + m * 16 + lr;
    qf[m][0] = *(const bf16x8*)(Qp + (size_t)qrow * 64 + g * 8);
    qf[m][1] = *(const bf16x8*)(Qp + (size_t)qrow * 64 + 32 + g * 8);
  }

  const int srow = t >> 3;
  const int sch  = (t & 7) ^ (srow & 7);
  const int so   = t * 16;

  auto stage = [&](int buf, int kt) {
    GLOAD_LDS16(Kp + (size_t)(kt * 64 + srow) * 64 + sch * 8, (char*)&K_lds[buf][0] + so);
    GLOAD_LDS16(Vt + (size_t)srow * 1024 + kt * 64 + sch * 8, (char*)&V_lds[buf][0] + so);
  };

  f32x4 o_acc[2][4] = {};
  float den[2][4] = {};

  stage(0, 0);
  __syncthreads();
  int buf = 0;
  for (int kt = 0; kt < 16; kt++) {
    if (kt + 1 < 16) stage(buf ^ 1, kt + 1);

    // QK^T: S[q in wave's 32][k in 0..63]; kf shared across both m-frags
    f32x4 s4[2][4] = {};
    __builtin_amdgcn_s_setprio(1);
    #pragma unroll
    for (int ks = 0; ks < 4; ks++) {
      int krow = ks * 16 + lr;
      #pragma unroll
      for (int c = 0; c < 2; c++) {
        bf16x8 kf = *(const bf16x8*)((char*)&K_lds[buf][0] + krow * 128 +
                                     ((c * 64 + g * 16) ^ ((krow & 7) << 4)));
        #pragma unroll
        for (int m = 0; m < 2; m++)
          s4[m][ks] = __builtin_amdgcn_mfma_f32_16x16x32_bf16(qf[m][c], kf, s4[m][ks], 0, 0, 0);
      }
    }
    __builtin_amdgcn_s_setprio(0);

    // exp + P to LDS (wave-local rows)
    #pragma unroll
    for (int m = 0; m < 2; m++) {
      #pragma unroll
      for (int ks = 0; ks < 4; ks++) {
        #pragma unroll
        for (int r = 0; r < 4; r++) {
          float e = __expf(s4[m][ks][r]);
          den[m][r] += e;
          int q = wid * 32 + m * 16 + g * 4 + r;
          *(unsigned short*)((char*)P_lds + q * 128 +
                             (((ks * 16 + lr) * 2) ^ ((q & 7) << 4))) = f2bf(e);
        }
      }
    }

    bf16x8 pa[2][2];
    #pragma unroll
    for (int m = 0; m < 2; m++) {
      int q = wid * 32 + m * 16 + lr;
      #pragma unroll
      for (int c = 0; c < 2; c++)
        pa[m][c] = *(const bf16x8*)((char*)P_lds + q * 128 +
                                    ((c * 64 + g * 16) ^ ((q & 7) << 4)));
    }
    __builtin_amdgcn_s_setprio(1);
    #pragma unroll
    for (int ds_ = 0; ds_ < 4; ds_++) {
      int drow = ds_ * 16 + lr;
      #pragma unroll
      for (int c = 0; c < 2; c++) {
        bf16x8 vf = *(const bf16x8*)((char*)&V_lds[buf][0] + drow * 128 +
                                     ((c * 64 + g * 16) ^ ((drow & 7) << 4)));
        #pragma unroll
        for (int m = 0; m < 2; m++)
          o_acc[m][ds_] = __builtin_amdgcn_mfma_f32_16x16x32_bf16(pa[m][c], vf, o_acc[m][ds_], 0, 0, 0);
      }
    }
    __builtin_amdgcn_s_setprio(0);
    __syncthreads();
    buf ^= 1;
  }

  #pragma unroll
  for (int m = 0; m < 2; m++)
    #pragma unroll
    for (int r = 0; r < 4; r++) {
      den[m][r] += __shfl_xor(den[m][r], 1, 64);
      den[m][r] += __shfl_xor(den[m][r], 2, 64);
      den[m][r] += __shfl_xor(den[m][r], 4, 64);
      den[m][r] += __shfl_xor(den[m][r], 8, 64);
    }

  const int bb = bh >> 4, h = bh & 15;
  #pragma unroll
  for (int m = 0; m < 2; m++) {
    #pragma unroll
    for (int ds_ = 0; ds_ < 4; ds_++) {
      #pragma unroll
      for (int r = 0; r < 4; r++) {
        int q = qt * 256 + wid * 32 + m * 16 + g * 4 + r;
        int d = h * 64 + ds_ * 16 + lr;
        attn_out[((size_t)(bb * 1024 + q)) * 1024 + d] = f2bf(o_acc[m][ds_][r] / den[m][r]);
      }
    }
  }
}

// ---------------------------------------------------------------------------
extern "C" void kernel_launch(void* const* d_in, const int* in_sizes, int n_in,
                              void* d_out, int out_size, void* d_ws, size_t ws_size,
                              hipStream_t stream) {
  const float* x     = (const float*)d_in[0];
  const float* W_qkv = (const float*)d_in[1];
  const float* b_qkv = (const float*)d_in[2];
  const float* W_o   = (const float*)d_in[3];
  const float* b_o   = (const float*)d_in[4];
  float* out = (float*)d_out;

  unsigned short* ws      = (unsigned short*)d_ws;
  unsigned short* x_bf    = ws;                     //  8388608
  unsigned short* wqkv_t  = x_bf + 8388608;         //  3145728
  unsigned short* wo_t    = wqkv_t + 3145728;       //  1048576
  unsigned short* qkv     = wo_t + 1048576;         // 25165824 (3 x 2^23)
  unsigned short* attn_o  = qkv + 25165824;         //  8388608

  prep_fused<<<6144, 256, 0, stream>>>(x, x_bf, W_qkv, wqkv_t, W_o, wo_t);
  gemm256<0><<<dim3(12, 64), 512, 0, stream>>>(x_bf, wqkv_t, b_qkv, qkv, nullptr);
  attn_mfma<<<512, 512, 0, stream>>>(qkv, attn_o);
  gemm256<1><<<dim3(4, 64), 512, 0, stream>>>(attn_o, wo_t, b_o, nullptr, out);
}

// Round 13
// 163.005 us; speedup vs baseline: 1.0092x; 1.0092x over previous
//
#include <hip/hip_runtime.h>

// MHSA fwd MFMA bf16: B=8, N=1024, D=1024, H=16, DK=64. fp32 in/out, bf16 compute.
// Round 13: attention occupancy fix — P_lds halved to [128][32] (chunked PV),
// LDS 48.5->40KB, __launch_bounds__(512,8) => 4 blocks/CU, grid 1024 = exactly
// one round. GEMMs/prep unchanged from round 11 (best: 157.8us).

typedef __attribute__((ext_vector_type(8))) short bf16x8;
typedef __attribute__((ext_vector_type(4))) float f32x4;

#define GLOAD_LDS16(gp, lp)                                                              \
  __builtin_amdgcn_global_load_lds((const __attribute__((address_space(1))) void*)(gp),  \
                                   (__attribute__((address_space(3))) void*)(lp), 16, 0, 0)

__device__ __forceinline__ unsigned short f2bf(float f) {
  unsigned int u = __float_as_uint(f);
  u += 0x7fffu + ((u >> 16) & 1u);          // RNE
  return (unsigned short)(u >> 16);
}

// ---------------------------------------------------------------------------
// Fused pre-pass: blocks [0,2048) cast x->bf16; [2048,5120) transpose W_qkv;
// [5120,6144) transpose W_o.
// ---------------------------------------------------------------------------
__global__ __launch_bounds__(256) void prep_fused(
    const float* __restrict__ x, unsigned short* __restrict__ x_bf,
    const float* __restrict__ W_qkv, unsigned short* __restrict__ wqkv_t,
    const float* __restrict__ W_o, unsigned short* __restrict__ wo_t) {
  const int b = blockIdx.x;
  if (b < 2048) {
    const int n4 = 8388608 / 4;
    for (int i = b * 256 + threadIdx.x; i < n4; i += 2048 * 256) {
      float4 v = reinterpret_cast<const float4*>(x)[i];
      ushort4 o;
      o.x = f2bf(v.x); o.y = f2bf(v.y); o.z = f2bf(v.z); o.w = f2bf(v.w);
      reinterpret_cast<ushort4*>(x_bf)[i] = o;
    }
  } else {
    __shared__ float tile[32][33];
    const float* W;
    unsigned short* Wt;
    int R = 1024, C, bx, by;
    if (b < 5120) {
      W = W_qkv; Wt = wqkv_t; C = 3072;
      int bb = b - 2048; bx = bb % 96; by = bb / 96;
    } else {
      W = W_o; Wt = wo_t; C = 1024;
      int bb = b - 5120; bx = bb & 31; by = bb >> 5;
    }
    const int tx = threadIdx.x & 31, ty = threadIdx.x >> 5;
    const int c0 = bx * 32, r0 = by * 32;
    #pragma unroll
    for (int i = 0; i < 4; i++) {
      int r = r0 + ty + i * 8;
      tile[ty + i * 8][tx] = W[(size_t)r * C + c0 + tx];
    }
    __syncthreads();
    #pragma unroll
    for (int i = 0; i < 4; i++) {
      int c = c0 + ty + i * 8;
      Wt[(size_t)c * R + r0 + tx] = f2bf(tile[tx][ty + i * 8]);
    }
  }
}

// ---------------------------------------------------------------------------
// GEMM (round-6 proven config): 128x256, BK=64, 512 thr (8 waves = 2M x 4N;
// 64x64 per wave). 3-buf LDS; tile kt+2 staged during tile kt; tile-top
// vmcnt(6). 2 phases x 16 MFMA.
// MODE 0: qkv scatter (Q pre-scaled 0.125, V transposed per head). MODE 1: f32.
// ---------------------------------------------------------------------------
template <int MODE>
__global__ __launch_bounds__(512) void gemm256(
    const unsigned short* __restrict__ A, const unsigned short* __restrict__ Bt,
    const float* __restrict__ bias, unsigned short* __restrict__ qkv_out,
    float* __restrict__ Cout) {
  __shared__ __align__(16) unsigned short As[3][128 * 64];   // 48 KB
  __shared__ __align__(16) unsigned short Bs[3][256 * 64];   // 96 KB
  const int t = threadIdx.x;
  const int lane = t & 63, wid = t >> 6;
  const int lr = lane & 15, g = lane >> 4;
  const int wm = wid >> 2, wn = wid & 3;

  const int nwg = gridDim.x * gridDim.y;
  const int id = blockIdx.x + gridDim.x * blockIdx.y;
  const int sw = (id & 7) * (nwg >> 3) + (id >> 3);
  const int bx = sw % gridDim.x, by = sw / gridDim.x;
  const int row0 = by * 128, col0 = bx * 256;

  const int srow = t >> 3, sch = t & 7;     // 64 rows of 128B

  auto stA = [&](int buf, int kt, int j) {  // j=0..1
    int row = j * 64 + srow;
    int ch = sch ^ (row & 7);
    GLOAD_LDS16(A + (size_t)(row0 + row) * 1024 + kt * 64 + ch * 8,
                (char*)&As[buf][0] + j * 8192 + t * 16);
  };
  auto stB = [&](int buf, int kt, int j) {  // j=0..3
    int row = j * 64 + srow;
    int ch = sch ^ (row & 7);
    GLOAD_LDS16(Bt + (size_t)(col0 + row) * 1024 + kt * 64 + ch * 8,
                (char*)&Bs[buf][0] + j * 8192 + t * 16);
  };
  auto rdA = [&](int buf, int c, int m) -> bf16x8 {
    int r = wm * 64 + m * 16 + lr;
    return *(const bf16x8*)((const char*)&As[buf][0] + r * 128 +
                            ((c * 64 + g * 16) ^ ((r & 7) << 4)));
  };
  auto rdB = [&](int buf, int c, int n) -> bf16x8 {
    int r = wn * 64 + n * 16 + lr;
    return *(const bf16x8*)((const char*)&Bs[buf][0] + r * 128 +
                            ((c * 64 + g * 16) ^ ((r & 7) << 4)));
  };

  f32x4 acc[4][4] = {};

  stA(0, 0, 0); stA(0, 0, 1);
  stB(0, 0, 0); stB(0, 0, 1); stB(0, 0, 2); stB(0, 0, 3);
  stA(1, 1, 0); stA(1, 1, 1);
  stB(1, 1, 0); stB(1, 1, 1); stB(1, 1, 2); stB(1, 1, 3);
  asm volatile("s_waitcnt vmcnt(6)" ::: "memory");
  __builtin_amdgcn_s_barrier();

  for (int kt = 0; kt < 16; kt++) {
    const int buf = kt % 3;
    const int bufn = (kt + 2) % 3;
    const bool pf = (kt <= 13);
    if (kt > 0) {
      if (kt == 15) asm volatile("s_waitcnt vmcnt(0)" ::: "memory");
      else          asm volatile("s_waitcnt vmcnt(6)" ::: "memory");
      __builtin_amdgcn_s_barrier();
    }

    // ---- phase 0: k-step 0 ----
    bf16x8 a0[4], b0[4];
    #pragma unroll
    for (int m = 0; m < 4; m++) a0[m] = rdA(buf, 0, m);
    #pragma unroll
    for (int n = 0; n < 4; n++) b0[n] = rdB(buf, 0, n);
    if (pf) { stA(bufn, kt + 2, 0); stA(bufn, kt + 2, 1); stB(bufn, kt + 2, 0); }
    __builtin_amdgcn_s_barrier();
    asm volatile("s_waitcnt lgkmcnt(0)" ::: "memory");
    __builtin_amdgcn_sched_barrier(0);
    __builtin_amdgcn_s_setprio(1);
    #pragma unroll
    for (int m = 0; m < 4; m++)
      #pragma unroll
      for (int n = 0; n < 4; n++)
        acc[m][n] = __builtin_amdgcn_mfma_f32_16x16x32_bf16(a0[m], b0[n], acc[m][n], 0, 0, 0);
    __builtin_amdgcn_s_setprio(0);
    __builtin_amdgcn_s_barrier();

    // ---- phase 1: k-step 1 ----
    bf16x8 a1[4], b1[4];
    #pragma unroll
    for (int m = 0; m < 4; m++) a1[m] = rdA(buf, 1, m);
    #pragma unroll
    for (int n = 0; n < 4; n++) b1[n] = rdB(buf, 1, n);
    if (pf) { stB(bufn, kt + 2, 1); stB(bufn, kt + 2, 2); stB(bufn, kt + 2, 3); }
    __builtin_amdgcn_s_barrier();
    asm volatile("s_waitcnt lgkmcnt(0)" ::: "memory");
    __builtin_amdgcn_sched_barrier(0);
    __builtin_amdgcn_s_setprio(1);
    #pragma unroll
    for (int m = 0; m < 4; m++)
      #pragma unroll
      for (int n = 0; n < 4; n++)
        acc[m][n] = __builtin_amdgcn_mfma_f32_16x16x32_bf16(a1[m], b1[n], acc[m][n], 0, 0, 0);
    __builtin_amdgcn_s_setprio(0);
    __builtin_amdgcn_s_barrier();
  }

  // ---------------- epilogue ----------------
  if (MODE == 0) {
    const int which = col0 >> 10;   // block-uniform (1024 % 256 == 0)
    if (which == 2) {
      #pragma unroll
      for (int m = 0; m < 4; m++) {
        int row = row0 + wm * 64 + m * 16 + g * 4;
        int bb = row >> 10, nn = row & 1023;
        #pragma unroll
        for (int n = 0; n < 4; n++) {
          int col = col0 + wn * 64 + n * 16 + lr;
          int cc = col & 1023;
          int h = cc >> 6, dk = cc & 63;
          float bv = bias[col];
          ushort4 w;
          w.x = f2bf(acc[m][n][0] + bv);
          w.y = f2bf(acc[m][n][1] + bv);
          w.z = f2bf(acc[m][n][2] + bv);
          w.w = f2bf(acc[m][n][3] + bv);
          size_t idx = ((size_t)2 << 23) + (((size_t)(bb * 16 + h)) << 16) +
                       (size_t)dk * 1024 + nn;
          *(ushort4*)(qkv_out + idx) = w;
        }
      }
    } else {
      #pragma unroll
      for (int m = 0; m < 4; m++) {
        #pragma unroll
        for (int n = 0; n < 4; n++) {
          int col = col0 + wn * 64 + n * 16 + lr;
          int cc = col & 1023;
          int h = cc >> 6, dk = cc & 63;
          #pragma unroll
          for (int r = 0; r < 4; r++) {
            int row = row0 + wm * 64 + m * 16 + g * 4 + r;
            int bb = row >> 10, nn = row & 1023;
            float v = acc[m][n][r] + bias[col];
            if (which == 0) v *= 0.125f;   // fold 1/sqrt(dk) into Q
            size_t idx = ((size_t)which << 23) +
                         (((size_t)((bb * 16 + h) * 1024 + nn)) << 6) + dk;
            qkv_out[idx] = f2bf(v);
          }
        }
      }
    }
  } else {
    #pragma unroll
    for (int m = 0; m < 4; m++) {
      #pragma unroll
      for (int n = 0; n < 4; n++) {
        int col = col0 + wn * 64 + n * 16 + lr;
        #pragma unroll
        for (int r = 0; r < 4; r++) {
          int row = row0 + wm * 64 + m * 16 + g * 4 + r;
          Cout[(size_t)row * 1024 + col] = acc[m][n][r] + bias[col];
        }
      }
    }
  }
}

// ---------------------------------------------------------------------------
// Attention v6: 8 waves, QBLK=128, KVBLK=64, dbuf K+V via swizzled
// global_load_lds (R11 skeleton). P_lds halved to [128][32] (8KB): PV done in
// two 32-k chunks, P buffer reused per chunk (wave-local, in-order).
// LDS = 16+16+8 = 40KB -> 4 blocks/CU; launch_bounds(512,8) targets 64 VGPR.
// Grid 1024 = 4/CU x 256 = exactly one scheduling round.
// ---------------------------------------------------------------------------
__global__ __launch_bounds__(512, 8) void attn_mfma(
    const unsigned short* __restrict__ qkv, unsigned short* __restrict__ attn_out) {
  __shared__ __align__(16) unsigned short K_lds[2][64 * 64];   // [k][d] swz, 16 KB
  __shared__ __align__(16) unsigned short V_lds[2][64 * 64];   // [d][k] swz, 16 KB
  __shared__ __align__(16) unsigned short P_half[128 * 32];    // [q][k'] swz, 8 KB

  const int bid = ((blockIdx.x & 7) << 7) + (blockIdx.x >> 3);
  const int bh = bid >> 3, qt = bid & 7;
  const unsigned short* Qp = qkv + ((size_t)bh << 16);
  const unsigned short* Kp = qkv + (1u << 23) + ((size_t)bh << 16);
  const unsigned short* Vt = qkv + (2u << 23) + ((size_t)bh << 16);  // [dk][n]

  const int t = threadIdx.x;
  const int lane = t & 63, wid = t >> 6;
  const int lr = lane & 15, g = lane >> 4;

  bf16x8 qf[2];
  {
    int qrow = qt * 128 + wid * 16 + lr;
    qf[0] = *(const bf16x8*)(Qp + (size_t)qrow * 64 + g * 8);
    qf[1] = *(const bf16x8*)(Qp + (size_t)qrow * 64 + 32 + g * 8);
  }

  const int srow = t >> 3;
  const int sch  = (t & 7) ^ (srow & 7);
  const int so   = t * 16;

  auto stage = [&](int buf, int kt) {
    GLOAD_LDS16(Kp + (size_t)(kt * 64 + srow) * 64 + sch * 8, (char*)&K_lds[buf][0] + so);
    GLOAD_LDS16(Vt + (size_t)srow * 1024 + kt * 64 + sch * 8, (char*)&V_lds[buf][0] + so);
  };

  f32x4 o_acc[4] = {};
  float den[4] = {0.f, 0.f, 0.f, 0.f};

  stage(0, 0);
  __syncthreads();
  int buf = 0;
  for (int kt = 0; kt < 16; kt++) {
    if (kt + 1 < 16) stage(buf ^ 1, kt + 1);

    // QK^T: S[q in wave's 16][k in 0..63]
    f32x4 s4[4] = {};
    __builtin_amdgcn_s_setprio(1);
    #pragma unroll
    for (int ks = 0; ks < 4; ks++) {
      int krow = ks * 16 + lr;
      #pragma unroll
      for (int c = 0; c < 2; c++) {
        bf16x8 kf = *(const bf16x8*)((char*)&K_lds[buf][0] + krow * 128 +
                                     ((c * 64 + g * 16) ^ ((krow & 7) << 4)));
        s4[ks] = __builtin_amdgcn_mfma_f32_16x16x32_bf16(qf[c], kf, s4[ks], 0, 0, 0);
      }
    }
    __builtin_amdgcn_s_setprio(0);

    // two 32-k chunks: exp -> P_half -> pa -> PV (wave-local buffer reuse)
    #pragma unroll
    for (int c = 0; c < 2; c++) {
      #pragma unroll
      for (int ks2 = 0; ks2 < 2; ks2++) {
        const int ks = c * 2 + ks2;
        #pragma unroll
        for (int r = 0; r < 4; r++) {
          float e = __expf(s4[ks][r]);
          den[r] += e;
          int q = wid * 16 + g * 4 + r;
          *(unsigned short*)((char*)P_half + q * 64 +
                             (((ks2 * 16 + lr) * 2) ^ ((q & 3) << 4))) = f2bf(e);
        }
      }
      bf16x8 pa;
      {
        int q = wid * 16 + lr;
        pa = *(const bf16x8*)((char*)P_half + q * 64 + ((g * 16) ^ ((q & 3) << 4)));
      }
      __builtin_amdgcn_s_setprio(1);
      #pragma unroll
      for (int ds_ = 0; ds_ < 4; ds_++) {
        int drow = ds_ * 16 + lr;
        bf16x8 vf = *(const bf16x8*)((char*)&V_lds[buf][0] + drow * 128 +
                                     ((c * 64 + g * 16) ^ ((drow & 7) << 4)));
        o_acc[ds_] = __builtin_amdgcn_mfma_f32_16x16x32_bf16(pa, vf, o_acc[ds_], 0, 0, 0);
      }
      __builtin_amdgcn_s_setprio(0);
    }
    __syncthreads();
    buf ^= 1;
  }

  #pragma unroll
  for (int r = 0; r < 4; r++) {
    den[r] += __shfl_xor(den[r], 1, 64);
    den[r] += __shfl_xor(den[r], 2, 64);
    den[r] += __shfl_xor(den[r], 4, 64);
    den[r] += __shfl_xor(den[r], 8, 64);
  }

  const int bb = bh >> 4, h = bh & 15;
  #pragma unroll
  for (int ds_ = 0; ds_ < 4; ds_++) {
    #pragma unroll
    for (int r = 0; r < 4; r++) {
      int q = qt * 128 + wid * 16 + g * 4 + r;
      int d = h * 64 + ds_ * 16 + lr;
      attn_out[((size_t)(bb * 1024 + q)) * 1024 + d] = f2bf(o_acc[ds_][r] / den[r]);
    }
  }
}

// ---------------------------------------------------------------------------
extern "C" void kernel_launch(void* const* d_in, const int* in_sizes, int n_in,
                              void* d_out, int out_size, void* d_ws, size_t ws_size,
                              hipStream_t stream) {
  const float* x     = (const float*)d_in[0];
  const float* W_qkv = (const float*)d_in[1];
  const float* b_qkv = (const float*)d_in[2];
  const float* W_o   = (const float*)d_in[3];
  const float* b_o   = (const float*)d_in[4];
  float* out = (float*)d_out;

  unsigned short* ws      = (unsigned short*)d_ws;
  unsigned short* x_bf    = ws;                     //  8388608
  unsigned short* wqkv_t  = x_bf + 8388608;         //  3145728
  unsigned short* wo_t    = wqkv_t + 3145728;       //  1048576
  unsigned short* qkv     = wo_t + 1048576;         // 25165824 (3 x 2^23)
  unsigned short* attn_o  = qkv + 25165824;         //  8388608

  prep_fused<<<6144, 256, 0, stream>>>(x, x_bf, W_qkv, wqkv_t, W_o, wo_t);
  gemm256<0><<<dim3(12, 64), 512, 0, stream>>>(x_bf, wqkv_t, b_qkv, qkv, nullptr);
  attn_mfma<<<1024, 512, 0, stream>>>(qkv, attn_o);
  gemm256<1><<<dim3(4, 64), 512, 0, stream>>>(attn_o, wo_t, b_o, nullptr, out);
}

// Round 14
// 154.649 us; speedup vs baseline: 1.0637x; 1.0540x over previous
//
#include <hip/hip_runtime.h>

// MHSA fwd MFMA bf16: B=8, N=1024, D=1024, H=16, DK=64. fp32 in/out, bf16 compute.
// Round 14: GEMM barrier reduction — mid-tile barriers removed (proven
// unnecessary by hazard analysis); 1 barrier + 1 counted vmcnt per K-tile;
// compiler free-schedules ds_read/MFMA/staging. Attention reverted to R11
// (proven 49us). prep_fused kept.

typedef __attribute__((ext_vector_type(8))) short bf16x8;
typedef __attribute__((ext_vector_type(4))) float f32x4;

#define GLOAD_LDS16(gp, lp)                                                              \
  __builtin_amdgcn_global_load_lds((const __attribute__((address_space(1))) void*)(gp),  \
                                   (__attribute__((address_space(3))) void*)(lp), 16, 0, 0)

__device__ __forceinline__ unsigned short f2bf(float f) {
  unsigned int u = __float_as_uint(f);
  u += 0x7fffu + ((u >> 16) & 1u);          // RNE
  return (unsigned short)(u >> 16);
}

// ---------------------------------------------------------------------------
// Fused pre-pass: blocks [0,2048) cast x->bf16; [2048,5120) transpose W_qkv;
// [5120,6144) transpose W_o.
// ---------------------------------------------------------------------------
__global__ __launch_bounds__(256) void prep_fused(
    const float* __restrict__ x, unsigned short* __restrict__ x_bf,
    const float* __restrict__ W_qkv, unsigned short* __restrict__ wqkv_t,
    const float* __restrict__ W_o, unsigned short* __restrict__ wo_t) {
  const int b = blockIdx.x;
  if (b < 2048) {
    const int n4 = 8388608 / 4;
    for (int i = b * 256 + threadIdx.x; i < n4; i += 2048 * 256) {
      float4 v = reinterpret_cast<const float4*>(x)[i];
      ushort4 o;
      o.x = f2bf(v.x); o.y = f2bf(v.y); o.z = f2bf(v.z); o.w = f2bf(v.w);
      reinterpret_cast<ushort4*>(x_bf)[i] = o;
    }
  } else {
    __shared__ float tile[32][33];
    const float* W;
    unsigned short* Wt;
    int R = 1024, C, bx, by;
    if (b < 5120) {
      W = W_qkv; Wt = wqkv_t; C = 3072;
      int bb = b - 2048; bx = bb % 96; by = bb / 96;
    } else {
      W = W_o; Wt = wo_t; C = 1024;
      int bb = b - 5120; bx = bb & 31; by = bb >> 5;
    }
    const int tx = threadIdx.x & 31, ty = threadIdx.x >> 5;
    const int c0 = bx * 32, r0 = by * 32;
    #pragma unroll
    for (int i = 0; i < 4; i++) {
      int r = r0 + ty + i * 8;
      tile[ty + i * 8][tx] = W[(size_t)r * C + c0 + tx];
    }
    __syncthreads();
    #pragma unroll
    for (int i = 0; i < 4; i++) {
      int c = c0 + ty + i * 8;
      Wt[(size_t)c * R + r0 + tx] = f2bf(tile[tx][ty + i * 8]);
    }
  }
}

// ---------------------------------------------------------------------------
// GEMM v2 (relaxed schedule): 128x256, BK=64, 512 thr (8 waves = 2M x 4N;
// 64x64 per wave). 3-buf LDS; tile kt+2 staged during tile kt; ONE tile-top
// counted vmcnt(6) + s_barrier + sched_barrier per K-tile; no mid barriers —
// compiler free-schedules 16 ds_read_b128 + 6 gload_lds + 32 MFMA per tile,
// waves drift for cross-wave LDS/MFMA overlap.
// MODE 0: qkv scatter (Q pre-scaled 0.125, V transposed per head). MODE 1: f32.
// ---------------------------------------------------------------------------
template <int MODE>
__global__ __launch_bounds__(512) void gemm256(
    const unsigned short* __restrict__ A, const unsigned short* __restrict__ Bt,
    const float* __restrict__ bias, unsigned short* __restrict__ qkv_out,
    float* __restrict__ Cout) {
  __shared__ __align__(16) unsigned short As[3][128 * 64];   // 48 KB
  __shared__ __align__(16) unsigned short Bs[3][256 * 64];   // 96 KB
  const int t = threadIdx.x;
  const int lane = t & 63, wid = t >> 6;
  const int lr = lane & 15, g = lane >> 4;
  const int wm = wid >> 2, wn = wid & 3;

  const int nwg = gridDim.x * gridDim.y;
  const int id = blockIdx.x + gridDim.x * blockIdx.y;
  const int sw = (id & 7) * (nwg >> 3) + (id >> 3);
  const int bx = sw % gridDim.x, by = sw / gridDim.x;
  const int row0 = by * 128, col0 = bx * 256;

  const int srow = t >> 3, sch = t & 7;     // 64 rows of 128B

  auto stA = [&](int buf, int kt, int j) {  // j=0..1
    int row = j * 64 + srow;
    int ch = sch ^ (row & 7);
    GLOAD_LDS16(A + (size_t)(row0 + row) * 1024 + kt * 64 + ch * 8,
                (char*)&As[buf][0] + j * 8192 + t * 16);
  };
  auto stB = [&](int buf, int kt, int j) {  // j=0..3
    int row = j * 64 + srow;
    int ch = sch ^ (row & 7);
    GLOAD_LDS16(Bt + (size_t)(col0 + row) * 1024 + kt * 64 + ch * 8,
                (char*)&Bs[buf][0] + j * 8192 + t * 16);
  };
  auto rdA = [&](int buf, int c, int m) -> bf16x8 {
    int r = wm * 64 + m * 16 + lr;
    return *(const bf16x8*)((const char*)&As[buf][0] + r * 128 +
                            ((c * 64 + g * 16) ^ ((r & 7) << 4)));
  };
  auto rdB = [&](int buf, int c, int n) -> bf16x8 {
    int r = wn * 64 + n * 16 + lr;
    return *(const bf16x8*)((const char*)&Bs[buf][0] + r * 128 +
                            ((c * 64 + g * 16) ^ ((r & 7) << 4)));
  };

  f32x4 acc[4][4] = {};

  stA(0, 0, 0); stA(0, 0, 1);
  stB(0, 0, 0); stB(0, 0, 1); stB(0, 0, 2); stB(0, 0, 3);
  stA(1, 1, 0); stA(1, 1, 1);
  stB(1, 1, 0); stB(1, 1, 1); stB(1, 1, 2); stB(1, 1, 3);

  for (int kt = 0; kt < 16; kt++) {
    const int buf = kt % 3;
    const int bufn = (kt + 2) % 3;
    const bool pf = (kt <= 13);

    // tile-top: own 6 loads landed; next tile's 6 stay in flight
    if (kt == 15) asm volatile("s_waitcnt vmcnt(0)" ::: "memory");
    else          asm volatile("s_waitcnt vmcnt(6)" ::: "memory");
    __builtin_amdgcn_s_barrier();
    __builtin_amdgcn_sched_barrier(0);   // staging below must not hoist above

    // k-step 0
    bf16x8 a0[4], b0[4];
    #pragma unroll
    for (int m = 0; m < 4; m++) a0[m] = rdA(buf, 0, m);
    #pragma unroll
    for (int n = 0; n < 4; n++) b0[n] = rdB(buf, 0, n);
    if (pf) { stA(bufn, kt + 2, 0); stA(bufn, kt + 2, 1); stB(bufn, kt + 2, 0); }
    #pragma unroll
    for (int m = 0; m < 4; m++)
      #pragma unroll
      for (int n = 0; n < 4; n++)
        acc[m][n] = __builtin_amdgcn_mfma_f32_16x16x32_bf16(a0[m], b0[n], acc[m][n], 0, 0, 0);

    // k-step 1
    bf16x8 a1[4], b1[4];
    #pragma unroll
    for (int m = 0; m < 4; m++) a1[m] = rdA(buf, 1, m);
    #pragma unroll
    for (int n = 0; n < 4; n++) b1[n] = rdB(buf, 1, n);
    if (pf) { stB(bufn, kt + 2, 1); stB(bufn, kt + 2, 2); stB(bufn, kt + 2, 3); }
    #pragma unroll
    for (int m = 0; m < 4; m++)
      #pragma unroll
      for (int n = 0; n < 4; n++)
        acc[m][n] = __builtin_amdgcn_mfma_f32_16x16x32_bf16(a1[m], b1[n], acc[m][n], 0, 0, 0);
    // no end barrier: next tile's top barrier provides the alignment point
  }

  // ---------------- epilogue ----------------
  if (MODE == 0) {
    const int which = col0 >> 10;   // block-uniform (1024 % 256 == 0)
    if (which == 2) {
      #pragma unroll
      for (int m = 0; m < 4; m++) {
        int row = row0 + wm * 64 + m * 16 + g * 4;
        int bb = row >> 10, nn = row & 1023;
        #pragma unroll
        for (int n = 0; n < 4; n++) {
          int col = col0 + wn * 64 + n * 16 + lr;
          int cc = col & 1023;
          int h = cc >> 6, dk = cc & 63;
          float bv = bias[col];
          ushort4 w;
          w.x = f2bf(acc[m][n][0] + bv);
          w.y = f2bf(acc[m][n][1] + bv);
          w.z = f2bf(acc[m][n][2] + bv);
          w.w = f2bf(acc[m][n][3] + bv);
          size_t idx = ((size_t)2 << 23) + (((size_t)(bb * 16 + h)) << 16) +
                       (size_t)dk * 1024 + nn;
          *(ushort4*)(qkv_out + idx) = w;
        }
      }
    } else {
      #pragma unroll
      for (int m = 0; m < 4; m++) {
        #pragma unroll
        for (int n = 0; n < 4; n++) {
          int col = col0 + wn * 64 + n * 16 + lr;
          int cc = col & 1023;
          int h = cc >> 6, dk = cc & 63;
          #pragma unroll
          for (int r = 0; r < 4; r++) {
            int row = row0 + wm * 64 + m * 16 + g * 4 + r;
            int bb = row >> 10, nn = row & 1023;
            float v = acc[m][n][r] + bias[col];
            if (which == 0) v *= 0.125f;   // fold 1/sqrt(dk) into Q
            size_t idx = ((size_t)which << 23) +
                         (((size_t)((bb * 16 + h) * 1024 + nn)) << 6) + dk;
            qkv_out[idx] = f2bf(v);
          }
        }
      }
    }
  } else {
    #pragma unroll
    for (int m = 0; m < 4; m++) {
      #pragma unroll
      for (int n = 0; n < 4; n++) {
        int col = col0 + wn * 64 + n * 16 + lr;
        #pragma unroll
        for (int r = 0; r < 4; r++) {
          int row = row0 + wm * 64 + m * 16 + g * 4 + r;
          Cout[(size_t)row * 1024 + col] = acc[m][n][r] + bias[col];
        }
      }
    }
  }
}

// ---------------------------------------------------------------------------
// Attention (R11 proven version): 8 waves, QBLK=128, KVBLK=64. K and V^T
// staged via swizzled global_load_lds, double-buffered, prefetch before
// compute, one __syncthreads per tile. QK^T -> exp -> P_lds (wave-local) ->
// PV. No max-subtract; den shfl-reduced at end. setprio; XCD swizzle.
// ---------------------------------------------------------------------------
__global__ __launch_bounds__(512) void attn_mfma(
    const unsigned short* __restrict__ qkv, unsigned short* __restrict__ attn_out) {
  __shared__ __align__(16) unsigned short K_lds[2][64 * 64];   // [k][d] swz
  __shared__ __align__(16) unsigned short V_lds[2][64 * 64];   // [d][k] swz
  __shared__ __align__(16) unsigned short P_lds[128 * 64];     // [q][k] swz

  const int bid = ((blockIdx.x & 7) << 7) + (blockIdx.x >> 3);
  const int bh = bid >> 3, qt = bid & 7;
  const unsigned short* Qp = qkv + ((size_t)bh << 16);
  const unsigned short* Kp = qkv + (1u << 23) + ((size_t)bh << 16);
  const unsigned short* Vt = qkv + (2u << 23) + ((size_t)bh << 16);  // [dk][n]

  const int t = threadIdx.x;
  const int lane = t & 63, wid = t >> 6;
  const int lr = lane & 15, g = lane >> 4;

  bf16x8 qf[2];
  {
    int qrow = qt * 128 + wid * 16 + lr;
    qf[0] = *(const bf16x8*)(Qp + (size_t)qrow * 64 + g * 8);
    qf[1] = *(const bf16x8*)(Qp + (size_t)qrow * 64 + 32 + g * 8);
  }

  const int srow = t >> 3;
  const int sch  = (t & 7) ^ (srow & 7);
  const int so   = t * 16;

  auto stage = [&](int buf, int kt) {
    GLOAD_LDS16(Kp + (size_t)(kt * 64 + srow) * 64 + sch * 8, (char*)&K_lds[buf][0] + so);
    GLOAD_LDS16(Vt + (size_t)srow * 1024 + kt * 64 + sch * 8, (char*)&V_lds[buf][0] + so);
  };

  f32x4 o_acc[4] = {};
  float den[4] = {0.f, 0.f, 0.f, 0.f};

  stage(0, 0);
  __syncthreads();
  int buf = 0;
  for (int kt = 0; kt < 16; kt++) {
    if (kt + 1 < 16) stage(buf ^ 1, kt + 1);

    f32x4 s4[4] = {};
    __builtin_amdgcn_s_setprio(1);
    #pragma unroll
    for (int ks = 0; ks < 4; ks++) {
      int krow = ks * 16 + lr;
      #pragma unroll
      for (int c = 0; c < 2; c++) {
        bf16x8 kf = *(const bf16x8*)((char*)&K_lds[buf][0] + krow * 128 +
                                     ((c * 64 + g * 16) ^ ((krow & 7) << 4)));
        s4[ks] = __builtin_amdgcn_mfma_f32_16x16x32_bf16(qf[c], kf, s4[ks], 0, 0, 0);
      }
    }
    __builtin_amdgcn_s_setprio(0);

    #pragma unroll
    for (int ks = 0; ks < 4; ks++) {
      #pragma unroll
      for (int r = 0; r < 4; r++) {
        float e = __expf(s4[ks][r]);
        den[r] += e;
        int q = wid * 16 + g * 4 + r;
        *(unsigned short*)((char*)P_lds + q * 128 +
                           (((ks * 16 + lr) * 2) ^ ((q & 7) << 4))) = f2bf(e);
      }
    }

    bf16x8 pa[2];
    {
      int q = wid * 16 + lr;
      #pragma unroll
      for (int c = 0; c < 2; c++)
        pa[c] = *(const bf16x8*)((char*)P_lds + q * 128 +
                                 ((c * 64 + g * 16) ^ ((q & 7) << 4)));
    }
    __builtin_amdgcn_s_setprio(1);
    #pragma unroll
    for (int ds_ = 0; ds_ < 4; ds_++) {
      int drow = ds_ * 16 + lr;
      #pragma unroll
      for (int c = 0; c < 2; c++) {
        bf16x8 vf = *(const bf16x8*)((char*)&V_lds[buf][0] + drow * 128 +
                                     ((c * 64 + g * 16) ^ ((drow & 7) << 4)));
        o_acc[ds_] = __builtin_amdgcn_mfma_f32_16x16x32_bf16(pa[c], vf, o_acc[ds_], 0, 0, 0);
      }
    }
    __builtin_amdgcn_s_setprio(0);
    __syncthreads();
    buf ^= 1;
  }

  #pragma unroll
  for (int r = 0; r < 4; r++) {
    den[r] += __shfl_xor(den[r], 1, 64);
    den[r] += __shfl_xor(den[r], 2, 64);
    den[r] += __shfl_xor(den[r], 4, 64);
    den[r] += __shfl_xor(den[r], 8, 64);
  }

  const int bb = bh >> 4, h = bh & 15;
  #pragma unroll
  for (int ds_ = 0; ds_ < 4; ds_++) {
    #pragma unroll
    for (int r = 0; r < 4; r++) {
      int q = qt * 128 + wid * 16 + g * 4 + r;
      int d = h * 64 + ds_ * 16 + lr;
      attn_out[((size_t)(bb * 1024 + q)) * 1024 + d] = f2bf(o_acc[ds_][r] / den[r]);
    }
  }
}

// ---------------------------------------------------------------------------
extern "C" void kernel_launch(void* const* d_in, const int* in_sizes, int n_in,
                              void* d_out, int out_size, void* d_ws, size_t ws_size,
                              hipStream_t stream) {
  const float* x     = (const float*)d_in[0];
  const float* W_qkv = (const float*)d_in[1];
  const float* b_qkv = (const float*)d_in[2];
  const float* W_o   = (const float*)d_in[3];
  const float* b_o   = (const float*)d_in[4];
  float* out = (float*)d_out;

  unsigned short* ws      = (unsigned short*)d_ws;
  unsigned short* x_bf    = ws;                     //  8388608
  unsigned short* wqkv_t  = x_bf + 8388608;         //  3145728
  unsigned short* wo_t    = wqkv_t + 3145728;       //  1048576
  unsigned short* qkv     = wo_t + 1048576;         // 25165824 (3 x 2^23)
  unsigned short* attn_o  = qkv + 25165824;         //  8388608

  prep_fused<<<6144, 256, 0, stream>>>(x, x_bf, W_qkv, wqkv_t, W_o, wo_t);
  gemm256<0><<<dim3(12, 64), 512, 0, stream>>>(x_bf, wqkv_t, b_qkv, qkv, nullptr);
  attn_mfma<<<1024, 512, 0, stream>>>(qkv, attn_o);
  gemm256<1><<<dim3(4, 64), 512, 0, stream>>>(attn_o, wo_t, b_o, nullptr, out);
}

// Round 15
// 154.122 us; speedup vs baseline: 1.0674x; 1.0034x over previous
//
#include <hip/hip_runtime.h>

// MHSA fwd MFMA bf16: B=8, N=1024, D=1024, H=16, DK=64. fp32 in/out, bf16 compute.
// Round 15: attention v7 — swapped QK^T (s4 = mfma(K,Q)) so each lane holds
// P[q=lr][4 consecutive k]: P-writes become 4x ds_write_b64 per tile (was 16x
// b16), den becomes one scalar per lane (reduced once at end). GEMMs/prep
// unchanged from round 14 (best: 154.6us).

typedef __attribute__((ext_vector_type(8))) short bf16x8;
typedef __attribute__((ext_vector_type(4))) float f32x4;

#define GLOAD_LDS16(gp, lp)                                                              \
  __builtin_amdgcn_global_load_lds((const __attribute__((address_space(1))) void*)(gp),  \
                                   (__attribute__((address_space(3))) void*)(lp), 16, 0, 0)

__device__ __forceinline__ unsigned short f2bf(float f) {
  unsigned int u = __float_as_uint(f);
  u += 0x7fffu + ((u >> 16) & 1u);          // RNE
  return (unsigned short)(u >> 16);
}

// ---------------------------------------------------------------------------
// Fused pre-pass: blocks [0,2048) cast x->bf16; [2048,5120) transpose W_qkv;
// [5120,6144) transpose W_o.
// ---------------------------------------------------------------------------
__global__ __launch_bounds__(256) void prep_fused(
    const float* __restrict__ x, unsigned short* __restrict__ x_bf,
    const float* __restrict__ W_qkv, unsigned short* __restrict__ wqkv_t,
    const float* __restrict__ W_o, unsigned short* __restrict__ wo_t) {
  const int b = blockIdx.x;
  if (b < 2048) {
    const int n4 = 8388608 / 4;
    for (int i = b * 256 + threadIdx.x; i < n4; i += 2048 * 256) {
      float4 v = reinterpret_cast<const float4*>(x)[i];
      ushort4 o;
      o.x = f2bf(v.x); o.y = f2bf(v.y); o.z = f2bf(v.z); o.w = f2bf(v.w);
      reinterpret_cast<ushort4*>(x_bf)[i] = o;
    }
  } else {
    __shared__ float tile[32][33];
    const float* W;
    unsigned short* Wt;
    int R = 1024, C, bx, by;
    if (b < 5120) {
      W = W_qkv; Wt = wqkv_t; C = 3072;
      int bb = b - 2048; bx = bb % 96; by = bb / 96;
    } else {
      W = W_o; Wt = wo_t; C = 1024;
      int bb = b - 5120; bx = bb & 31; by = bb >> 5;
    }
    const int tx = threadIdx.x & 31, ty = threadIdx.x >> 5;
    const int c0 = bx * 32, r0 = by * 32;
    #pragma unroll
    for (int i = 0; i < 4; i++) {
      int r = r0 + ty + i * 8;
      tile[ty + i * 8][tx] = W[(size_t)r * C + c0 + tx];
    }
    __syncthreads();
    #pragma unroll
    for (int i = 0; i < 4; i++) {
      int c = c0 + ty + i * 8;
      Wt[(size_t)c * R + r0 + tx] = f2bf(tile[tx][ty + i * 8]);
    }
  }
}

// ---------------------------------------------------------------------------
// GEMM v2 (round-14 relaxed schedule): 128x256, BK=64, 512 thr (8 waves =
// 2M x 4N; 64x64 per wave). 3-buf LDS; tile kt+2 staged during tile kt; ONE
// tile-top counted vmcnt(6) + s_barrier + sched_barrier per K-tile.
// MODE 0: qkv scatter (Q pre-scaled 0.125, V transposed per head). MODE 1: f32.
// ---------------------------------------------------------------------------
template <int MODE>
__global__ __launch_bounds__(512) void gemm256(
    const unsigned short* __restrict__ A, const unsigned short* __restrict__ Bt,
    const float* __restrict__ bias, unsigned short* __restrict__ qkv_out,
    float* __restrict__ Cout) {
  __shared__ __align__(16) unsigned short As[3][128 * 64];   // 48 KB
  __shared__ __align__(16) unsigned short Bs[3][256 * 64];   // 96 KB
  const int t = threadIdx.x;
  const int lane = t & 63, wid = t >> 6;
  const int lr = lane & 15, g = lane >> 4;
  const int wm = wid >> 2, wn = wid & 3;

  const int nwg = gridDim.x * gridDim.y;
  const int id = blockIdx.x + gridDim.x * blockIdx.y;
  const int sw = (id & 7) * (nwg >> 3) + (id >> 3);
  const int bx = sw % gridDim.x, by = sw / gridDim.x;
  const int row0 = by * 128, col0 = bx * 256;

  const int srow = t >> 3, sch = t & 7;     // 64 rows of 128B

  auto stA = [&](int buf, int kt, int j) {  // j=0..1
    int row = j * 64 + srow;
    int ch = sch ^ (row & 7);
    GLOAD_LDS16(A + (size_t)(row0 + row) * 1024 + kt * 64 + ch * 8,
                (char*)&As[buf][0] + j * 8192 + t * 16);
  };
  auto stB = [&](int buf, int kt, int j) {  // j=0..3
    int row = j * 64 + srow;
    int ch = sch ^ (row & 7);
    GLOAD_LDS16(Bt + (size_t)(col0 + row) * 1024 + kt * 64 + ch * 8,
                (char*)&Bs[buf][0] + j * 8192 + t * 16);
  };
  auto rdA = [&](int buf, int c, int m) -> bf16x8 {
    int r = wm * 64 + m * 16 + lr;
    return *(const bf16x8*)((const char*)&As[buf][0] + r * 128 +
                            ((c * 64 + g * 16) ^ ((r & 7) << 4)));
  };
  auto rdB = [&](int buf, int c, int n) -> bf16x8 {
    int r = wn * 64 + n * 16 + lr;
    return *(const bf16x8*)((const char*)&Bs[buf][0] + r * 128 +
                            ((c * 64 + g * 16) ^ ((r & 7) << 4)));
  };

  f32x4 acc[4][4] = {};

  stA(0, 0, 0); stA(0, 0, 1);
  stB(0, 0, 0); stB(0, 0, 1); stB(0, 0, 2); stB(0, 0, 3);
  stA(1, 1, 0); stA(1, 1, 1);
  stB(1, 1, 0); stB(1, 1, 1); stB(1, 1, 2); stB(1, 1, 3);

  for (int kt = 0; kt < 16; kt++) {
    const int buf = kt % 3;
    const int bufn = (kt + 2) % 3;
    const bool pf = (kt <= 13);

    if (kt == 15) asm volatile("s_waitcnt vmcnt(0)" ::: "memory");
    else          asm volatile("s_waitcnt vmcnt(6)" ::: "memory");
    __builtin_amdgcn_s_barrier();
    __builtin_amdgcn_sched_barrier(0);   // staging below must not hoist above

    // k-step 0
    bf16x8 a0[4], b0[4];
    #pragma unroll
    for (int m = 0; m < 4; m++) a0[m] = rdA(buf, 0, m);
    #pragma unroll
    for (int n = 0; n < 4; n++) b0[n] = rdB(buf, 0, n);
    if (pf) { stA(bufn, kt + 2, 0); stA(bufn, kt + 2, 1); stB(bufn, kt + 2, 0); }
    #pragma unroll
    for (int m = 0; m < 4; m++)
      #pragma unroll
      for (int n = 0; n < 4; n++)
        acc[m][n] = __builtin_amdgcn_mfma_f32_16x16x32_bf16(a0[m], b0[n], acc[m][n], 0, 0, 0);

    // k-step 1
    bf16x8 a1[4], b1[4];
    #pragma unroll
    for (int m = 0; m < 4; m++) a1[m] = rdA(buf, 1, m);
    #pragma unroll
    for (int n = 0; n < 4; n++) b1[n] = rdB(buf, 1, n);
    if (pf) { stB(bufn, kt + 2, 1); stB(bufn, kt + 2, 2); stB(bufn, kt + 2, 3); }
    #pragma unroll
    for (int m = 0; m < 4; m++)
      #pragma unroll
      for (int n = 0; n < 4; n++)
        acc[m][n] = __builtin_amdgcn_mfma_f32_16x16x32_bf16(a1[m], b1[n], acc[m][n], 0, 0, 0);
  }

  // ---------------- epilogue ----------------
  if (MODE == 0) {
    const int which = col0 >> 10;   // block-uniform (1024 % 256 == 0)
    if (which == 2) {
      #pragma unroll
      for (int m = 0; m < 4; m++) {
        int row = row0 + wm * 64 + m * 16 + g * 4;
        int bb = row >> 10, nn = row & 1023;
        #pragma unroll
        for (int n = 0; n < 4; n++) {
          int col = col0 + wn * 64 + n * 16 + lr;
          int cc = col & 1023;
          int h = cc >> 6, dk = cc & 63;
          float bv = bias[col];
          ushort4 w;
          w.x = f2bf(acc[m][n][0] + bv);
          w.y = f2bf(acc[m][n][1] + bv);
          w.z = f2bf(acc[m][n][2] + bv);
          w.w = f2bf(acc[m][n][3] + bv);
          size_t idx = ((size_t)2 << 23) + (((size_t)(bb * 16 + h)) << 16) +
                       (size_t)dk * 1024 + nn;
          *(ushort4*)(qkv_out + idx) = w;
        }
      }
    } else {
      #pragma unroll
      for (int m = 0; m < 4; m++) {
        #pragma unroll
        for (int n = 0; n < 4; n++) {
          int col = col0 + wn * 64 + n * 16 + lr;
          int cc = col & 1023;
          int h = cc >> 6, dk = cc & 63;
          #pragma unroll
          for (int r = 0; r < 4; r++) {
            int row = row0 + wm * 64 + m * 16 + g * 4 + r;
            int bb = row >> 10, nn = row & 1023;
            float v = acc[m][n][r] + bias[col];
            if (which == 0) v *= 0.125f;   // fold 1/sqrt(dk) into Q
            size_t idx = ((size_t)which << 23) +
                         (((size_t)((bb * 16 + h) * 1024 + nn)) << 6) + dk;
            qkv_out[idx] = f2bf(v);
          }
        }
      }
    }
  } else {
    #pragma unroll
    for (int m = 0; m < 4; m++) {
      #pragma unroll
      for (int n = 0; n < 4; n++) {
        int col = col0 + wn * 64 + n * 16 + lr;
        #pragma unroll
        for (int r = 0; r < 4; r++) {
          int row = row0 + wm * 64 + m * 16 + g * 4 + r;
          Cout[(size_t)row * 1024 + col] = acc[m][n][r] + bias[col];
        }
      }
    }
  }
}

// ---------------------------------------------------------------------------
// Attention v7: 8 waves, QBLK=128, KVBLK=64, dbuf K+V via swizzled
// global_load_lds (R11 skeleton). SWAPPED QK^T: s4[ks] = mfma(kf, qf) so lane
// (lr,g) holds P[q=lr][k=ks*16+g*4+{0..3}] -> one packed ds_write_b64 per ks
// (4 writes/tile vs 16), den is one scalar per lane (reduced at end via
// shfl_xor 16,32 + 4 lane-shuffles). PV unchanged.
// ---------------------------------------------------------------------------
__global__ __launch_bounds__(512) void attn_mfma(
    const unsigned short* __restrict__ qkv, unsigned short* __restrict__ attn_out) {
  __shared__ __align__(16) unsigned short K_lds[2][64 * 64];   // [k][d] swz
  __shared__ __align__(16) unsigned short V_lds[2][64 * 64];   // [d][k] swz
  __shared__ __align__(16) unsigned short P_lds[128 * 64];     // [q][k] swz

  const int bid = ((blockIdx.x & 7) << 7) + (blockIdx.x >> 3);
  const int bh = bid >> 3, qt = bid & 7;
  const unsigned short* Qp = qkv + ((size_t)bh << 16);
  const unsigned short* Kp = qkv + (1u << 23) + ((size_t)bh << 16);
  const unsigned short* Vt = qkv + (2u << 23) + ((size_t)bh << 16);  // [dk][n]

  const int t = threadIdx.x;
  const int lane = t & 63, wid = t >> 6;
  const int lr = lane & 15, g = lane >> 4;

  bf16x8 qf[2];
  {
    int qrow = qt * 128 + wid * 16 + lr;
    qf[0] = *(const bf16x8*)(Qp + (size_t)qrow * 64 + g * 8);
    qf[1] = *(const bf16x8*)(Qp + (size_t)qrow * 64 + 32 + g * 8);
  }

  const int srow = t >> 3;
  const int sch  = (t & 7) ^ (srow & 7);
  const int so   = t * 16;

  auto stage = [&](int buf, int kt) {
    GLOAD_LDS16(Kp + (size_t)(kt * 64 + srow) * 64 + sch * 8, (char*)&K_lds[buf][0] + so);
    GLOAD_LDS16(Vt + (size_t)srow * 1024 + kt * 64 + sch * 8, (char*)&V_lds[buf][0] + so);
  };

  f32x4 o_acc[4] = {};
  float den_l = 0.f;                 // per-lane scalar: q=lr, k-subset (g,ks)
  const int qrow_w = wid * 16 + lr;  // P row this lane writes

  stage(0, 0);
  __syncthreads();
  int buf = 0;
  for (int kt = 0; kt < 16; kt++) {
    if (kt + 1 < 16) stage(buf ^ 1, kt + 1);

    // swapped QK^T: D[k][q] -> lane holds q=lr, k=ks*16+g*4+r
    f32x4 s4[4] = {};
    __builtin_amdgcn_s_setprio(1);
    #pragma unroll
    for (int ks = 0; ks < 4; ks++) {
      int krow = ks * 16 + lr;
      #pragma unroll
      for (int c = 0; c < 2; c++) {
        bf16x8 kf = *(const bf16x8*)((char*)&K_lds[buf][0] + krow * 128 +
                                     ((c * 64 + g * 16) ^ ((krow & 7) << 4)));
        s4[ks] = __builtin_amdgcn_mfma_f32_16x16x32_bf16(kf, qf[c], s4[ks], 0, 0, 0);
      }
    }
    __builtin_amdgcn_s_setprio(0);

    // exp + packed P write: 4 consecutive k per lane -> one b64 per ks
    #pragma unroll
    for (int ks = 0; ks < 4; ks++) {
      float e0 = __expf(s4[ks][0]);
      float e1 = __expf(s4[ks][1]);
      float e2 = __expf(s4[ks][2]);
      float e3 = __expf(s4[ks][3]);
      den_l += (e0 + e1) + (e2 + e3);
      unsigned int lo = (unsigned int)f2bf(e0) | ((unsigned int)f2bf(e1) << 16);
      unsigned int hi = (unsigned int)f2bf(e2) | ((unsigned int)f2bf(e3) << 16);
      int k0 = ks * 16 + g * 4;
      *(uint2*)((char*)P_lds + qrow_w * 128 +
                ((k0 * 2) ^ ((qrow_w & 7) << 4))) = make_uint2(lo, hi);
    }

    bf16x8 pa[2];
    {
      int q = wid * 16 + lr;
      #pragma unroll
      for (int c = 0; c < 2; c++)
        pa[c] = *(const bf16x8*)((char*)P_lds + q * 128 +
                                 ((c * 64 + g * 16) ^ ((q & 7) << 4)));
    }
    __builtin_amdgcn_s_setprio(1);
    #pragma unroll
    for (int ds_ = 0; ds_ < 4; ds_++) {
      int drow = ds_ * 16 + lr;
      #pragma unroll
      for (int c = 0; c < 2; c++) {
        bf16x8 vf = *(const bf16x8*)((char*)&V_lds[buf][0] + drow * 128 +
                                     ((c * 64 + g * 16) ^ ((drow & 7) << 4)));
        o_acc[ds_] = __builtin_amdgcn_mfma_f32_16x16x32_bf16(pa[c], vf, o_acc[ds_], 0, 0, 0);
      }
    }
    __builtin_amdgcn_s_setprio(0);
    __syncthreads();
    buf ^= 1;
  }

  // den: reduce across g-groups (k-subsets); lane l then holds den(q=l&15)
  den_l += __shfl_xor(den_l, 16, 64);
  den_l += __shfl_xor(den_l, 32, 64);
  // realign to PV output rows: o_acc row q-in-16 = g*4+r
  float den_r[4];
  #pragma unroll
  for (int r = 0; r < 4; r++) den_r[r] = __shfl(den_l, g * 4 + r, 64);

  const int bb = bh >> 4, h = bh & 15;
  #pragma unroll
  for (int ds_ = 0; ds_ < 4; ds_++) {
    #pragma unroll
    for (int r = 0; r < 4; r++) {
      int q = qt * 128 + wid * 16 + g * 4 + r;
      int d = h * 64 + ds_ * 16 + lr;
      attn_out[((size_t)(bb * 1024 + q)) * 1024 + d] = f2bf(o_acc[ds_][r] / den_r[r]);
    }
  }
}

// ---------------------------------------------------------------------------
extern "C" void kernel_launch(void* const* d_in, const int* in_sizes, int n_in,
                              void* d_out, int out_size, void* d_ws, size_t ws_size,
                              hipStream_t stream) {
  const float* x     = (const float*)d_in[0];
  const float* W_qkv = (const float*)d_in[1];
  const float* b_qkv = (const float*)d_in[2];
  const float* W_o   = (const float*)d_in[3];
  const float* b_o   = (const float*)d_in[4];
  float* out = (float*)d_out;

  unsigned short* ws      = (unsigned short*)d_ws;
  unsigned short* x_bf    = ws;                     //  8388608
  unsigned short* wqkv_t  = x_bf + 8388608;         //  3145728
  unsigned short* wo_t    = wqkv_t + 3145728;       //  1048576
  unsigned short* qkv     = wo_t + 1048576;         // 25165824 (3 x 2^23)
  unsigned short* attn_o  = qkv + 25165824;         //  8388608

  prep_fused<<<6144, 256, 0, stream>>>(x, x_bf, W_qkv, wqkv_t, W_o, wo_t);
  gemm256<0><<<dim3(12, 64), 512, 0, stream>>>(x_bf, wqkv_t, b_qkv, qkv, nullptr);
  attn_mfma<<<1024, 512, 0, stream>>>(qkv, attn_o);
  gemm256<1><<<dim3(4, 64), 512, 0, stream>>>(attn_o, wo_t, b_o, nullptr, out);
}